// Round 4
// baseline (857.629 us; speedup 1.0000x reference)
//
#include <hip/hip_runtime.h>
#include <math.h>

#define BB 32
#define NN 128
#define SEQL 336
#define PREDL 96
#define DINC 16
#define DEMBC 32
#define HIDC 64
#define GG 8
#define KWIN 25
#define ENDC 34
#define TT 432

// workspace offsets (floats)
#define OFF_SEAS   0
#define OFF_TREND  (OFF_SEAS + BB*NN*SEQL)
#define OFF_GIN    (OFF_TREND + BB*NN*SEQL)
#define OFF_GOUT   (OFF_GIN + GG*BB*SEQL)
#define OFF_SEASO  (OFF_GOUT + GG*BB*PREDL)
#define OFF_TRENDO (OFF_SEASO + BB*NN*PREDL)
#define OFF_GX     (OFF_TRENDO + BB*NN*PREDL)
#define OFF_HIST   (OFF_GX + BB*TT*192)
// hist: former [32][336][64] then after [32][96][64]

// output offsets (floats)
#define OUT_FORMER 0
#define OUT_ATTF   (BB*NN*SEQL)
#define OUT_AFTER  (OUT_ATTF + BB*SEQL)
#define OUT_ATTA   (OUT_AFTER + BB*NN*PREDL)

__device__ __forceinline__ float fsig(float x) { return 1.0f/(1.0f + __expf(-x)); }
__device__ __forceinline__ float ftanh(float x) { return 1.0f - 2.0f/(__expf(2.0f*x) + 1.0f); }

// K1: per-group mean over member nodes + grouped residual head (fused)
__global__ __launch_bounds__(384) void k_gm_gout(const float* __restrict__ x,
                                                 const int* __restrict__ gi,
                                                 const float* __restrict__ w_res,
                                                 const float* __restrict__ b_res,
                                                 float* __restrict__ g_in,
                                                 float* __restrict__ g_out) {
    int g = blockIdx.x, b = blockIdx.y;
    __shared__ int sgi[NN];
    __shared__ float sg[SEQL];
    __shared__ float scnt;
    int tid = threadIdx.x;
    if (tid < NN) sgi[tid] = gi[tid];
    __syncthreads();
    if (tid == 0) {
        int c = 0;
        for (int n = 0; n < NN; n++) if (sgi[n] == g) c++;
        scnt = (float)c;
    }
    __syncthreads();
    float inv = 1.0f / scnt;
    for (int s = tid; s < SEQL; s += 384) {
        float sum = 0.0f;
        for (int n = 0; n < NN; n++)
            if (sgi[n] == g) sum += x[(b*NN + n)*SEQL + s];
        float v = sum * inv;
        sg[s] = v;
        g_in[(g*BB + b)*SEQL + s] = v;
    }
    __syncthreads();
    int p = tid;
    if (p < PREDL) {
        const float4* wr = (const float4*)(w_res + (g*PREDL + p)*SEQL);
        float acc = b_res[g*PREDL + p];
        #pragma unroll 4
        for (int s4 = 0; s4 < SEQL/4; s4++) {
            float4 w = wr[s4];
            float4 d = ((const float4*)sg)[s4];
            acc += w.x*d.x + w.y*d.y + w.z*d.z + w.w*d.w;
        }
        g_out[(g*BB + b)*PREDL + p] = acc;
    }
}

// K2: series decomposition: edge-padded moving average window 25
__global__ void k_decomp(const float* __restrict__ x, float* __restrict__ seasonal,
                         float* __restrict__ trend) {
    int idx = blockIdx.x*blockDim.x + threadIdx.x;
    if (idx >= BB*NN*SEQL) return;
    int t = idx % SEQL;
    int bn = idx / SEQL;
    const float* xr = x + bn*SEQL;
    float s = 0.0f;
    #pragma unroll
    for (int d = -12; d <= 12; d++) {
        int j = t + d;
        j = j < 0 ? 0 : (j >= SEQL ? SEQL-1 : j);
        s += xr[j];
    }
    float tr = s * (1.0f/KWIN);
    trend[idx] = tr;
    seasonal[idx] = xr[t] - tr;
}

// K3: per-node grouped seasonal/trend heads (SEQ->PRED), float4 everywhere
__global__ __launch_bounds__(128) void k_heads(const float* __restrict__ seasonal,
                                               const float* __restrict__ trend,
                                               const int* __restrict__ gi,
                                               const float* __restrict__ w_seas,
                                               const float* __restrict__ b_seas,
                                               const float* __restrict__ w_trend,
                                               const float* __restrict__ b_trend,
                                               float* __restrict__ seas_out,
                                               float* __restrict__ trend_out) {
    int bn = blockIdx.x;
    int n = bn % NN;
    int g = gi[n];
    __shared__ float ss[SEQL];
    __shared__ float st[SEQL];
    for (int s = threadIdx.x; s < SEQL/4; s += 128) {
        ((float4*)ss)[s] = ((const float4*)(seasonal + bn*SEQL))[s];
        ((float4*)st)[s] = ((const float4*)(trend + bn*SEQL))[s];
    }
    __syncthreads();
    int p = threadIdx.x;
    if (p < PREDL) {
        const float4* wsr = (const float4*)(w_seas + (g*PREDL + p)*SEQL);
        const float4* wtr = (const float4*)(w_trend + (g*PREDL + p)*SEQL);
        float a = b_seas[g*PREDL + p];
        float c = b_trend[g*PREDL + p];
        #pragma unroll 4
        for (int s4 = 0; s4 < SEQL/4; s4++) {
            float4 w0 = wsr[s4], w1 = wtr[s4];
            float4 d0 = ((const float4*)ss)[s4], d1 = ((const float4*)st)[s4];
            a += w0.x*d0.x + w0.y*d0.y + w0.z*d0.z + w0.w*d0.w;
            c += w1.x*d1.x + w1.y*d1.y + w1.z*d1.z + w1.w*d1.w;
        }
        seas_out[bn*PREDL + p] = a;
        trend_out[bn*PREDL + p] = c;
    }
}

// K4: mega-kernel: dy-emb + end-MLP outputs + node-mean + input-gate GEMM gx.
// Grid (7 t-tiles, 32 b), 512 thr = 64 t-lanes x 8 n-waves; wave w owns n = {w, w+8, ...}.
__global__ __launch_bounds__(512, 1) void k_mlp_all(
    const float* __restrict__ seasonal, const float* __restrict__ trend,
    const float* __restrict__ seas_out, const float* __restrict__ trend_out,
    const float* __restrict__ g_in, const float* __restrict__ g_out,
    const int* __restrict__ gi, const float* __restrict__ dy,
    const float* __restrict__ dy_w, const float* __restrict__ dy_b,
    const float* __restrict__ w1_end, const float* __restrict__ b1_end,
    const float* __restrict__ w2_end, const float* __restrict__ b2_end,
    const float* __restrict__ w_ih, const float* __restrict__ b_ih,
    const float* __restrict__ b_hh, float* __restrict__ gx,
    float* __restrict__ out)
{
    __shared__ float s_wih[192][35];   // +1 pad: stride 35 -> <=2-way bank alias (free)
    __shared__ float s_hsum[64][35];
    int tile = blockIdx.x;             // 0..6
    int b = blockIdx.y;                // 0..31
    int tid = threadIdx.x;
    int lane = tid & 63, wave = tid >> 6;
    int t = tile*64 + lane;
    bool tvalid = (t < TT);
    int tc = tvalid ? t : (TT-1);

    for (int i = tid; i < 192*ENDC; i += 512) s_wih[i/ENDC][i%ENDC] = w_ih[i];
    for (int i = tid; i < 64*35; i += 512) (&s_hsum[0][0])[i] = 0.0f;
    __syncthreads();

    float hsum[ENDC];
    #pragma unroll
    for (int e = 0; e < ENDC; e++) hsum[e] = 0.0f;

    int wbase = __builtin_amdgcn_readfirstlane(wave);   // per-wave scalar

    for (int ni = 0; ni < 16; ni++) {
        int n = wbase + ni*8;                 // scalar -> gi[n] is s_load
        int bn = b*NN + n;
        int g = gi[n];
        const float4* dyr = (const float4*)(dy + ((size_t)bn*TT + tc)*DINC);
        float4 d0 = dyr[0], d1 = dyr[1], d2 = dyr[2], d3 = dyr[3];
        float dv[DINC] = {d0.x,d0.y,d0.z,d0.w, d1.x,d1.y,d1.z,d1.w,
                          d2.x,d2.y,d2.z,d2.w, d3.x,d3.y,d3.z,d3.w};
        float hv[ENDC];
        #pragma unroll 4
        for (int e = 0; e < DEMBC; e++) {
            float a = dy_b[e];                // uniform -> sgpr
            #pragma unroll
            for (int i = 0; i < DINC; i++) a = fmaf(dv[i], dy_w[e*DINC + i], a);
            hv[2+e] = fmaxf(a, 0.0f);
        }
        float addv;
        if (tc < SEQL) {
            hv[0] = seasonal[bn*SEQL + tc];
            hv[1] = trend[bn*SEQL + tc];
            addv = g_in[(g*BB + b)*SEQL + tc];
        } else {
            int p = tc - SEQL;
            hv[0] = seas_out[bn*PREDL + p];
            hv[1] = trend_out[bn*PREDL + p];
            addv = g_out[(g*BB + b)*PREDL + p];
        }
        float acc = b2_end[g];
        const float* w1g = w1_end + g*HIDC*ENDC;
        const float* b1g = b1_end + g*HIDC;
        const float* w2g = w2_end + g*HIDC;
        #pragma unroll 4
        for (int hq = 0; hq < HIDC; hq++) {
            const float* wrow = w1g + hq*ENDC;   // uniform row -> s_load
            float a = b1g[hq];
            #pragma unroll
            for (int e = 0; e < ENDC; e++) a = fmaf(hv[e], wrow[e], a);
            acc = fmaf(fmaxf(a, 0.0f), w2g[hq], acc);
        }
        acc += addv;
        if (tvalid) {
            if (t < SEQL) out[OUT_FORMER + bn*SEQL + t] = acc;
            else          out[OUT_AFTER + bn*PREDL + (t - SEQL)] = acc;
        }
        #pragma unroll
        for (int e = 0; e < ENDC; e++) hsum[e] += hv[e];
    }

    // cross-wave reduction of hsum into s_hsum[lane][.]
    for (int w = 0; w < 8; w++) {
        if (wave == w) {
            #pragma unroll
            for (int e = 0; e < ENDC; e++) s_hsum[lane][e] += hsum[e];
        }
        __syncthreads();
    }
    for (int i = tid; i < 64*ENDC; i += 512) {
        int tt2 = i / ENDC, e = i % ENDC;
        s_hsum[tt2][e] *= (1.0f/NN);
    }
    __syncthreads();

    // gx for this (b, tile): 64 t x 192 j; consecutive tid -> consecutive j (coalesced)
    for (int it = 0; it < 24; it++) {
        int idx = tid + it*512;
        int j = idx % 192, tt2 = idx / 192;
        int tg = tile*64 + tt2;
        if (tg < TT) {
            float a = b_ih[j] + (j < 2*HIDC ? b_hh[j] : 0.0f);  // fold r,z hidden bias
            #pragma unroll
            for (int e = 0; e < ENDC; e++) a = fmaf(s_hsum[tt2][e], s_wih[j][e], a);
            gx[((size_t)b*TT + tg)*192 + j] = a;
        }
    }
}

// K5: dual GRU, standalone: 64 blocks x 64 threads.
// __launch_bounds__(64, 1): min 1 wave/EU -> VGPR cap 512, weights stay RESIDENT.
__global__ __launch_bounds__(64, 1) void k_gru(
    const float* __restrict__ gx, const float* __restrict__ w_hh,
    const float* __restrict__ b_hh, const float* __restrict__ w_ap,
    const float* __restrict__ b_ap, float* __restrict__ hist,
    float* __restrict__ out)
{
    __shared__ float hs[2*HIDC];
    int lane = threadIdx.x;
    int blk = blockIdx.x;
    int b = blk & 31;
    bool former = (blk < 32);
    int steps = former ? SEQL : PREDL;
    int t0 = former ? 0 : SEQL;
    float* hb = hist + (former ? (size_t)b*SEQL*HIDC
                               : (size_t)BB*SEQL*HIDC + (size_t)b*PREDL*HIDC);
    float wr_[HIDC], wz_[HIDC], wn_[HIDC];
    #pragma unroll
    for (int k = 0; k < HIDC; k++) wr_[k] = w_hh[lane*HIDC + k];
    #pragma unroll
    for (int k = 0; k < HIDC; k++) wz_[k] = w_hh[(lane+64)*HIDC + k];
    #pragma unroll
    for (int k = 0; k < HIDC; k++) wn_[k] = w_hh[(lane+128)*HIDC + k];
    float bhn = b_hh[lane + 128];
    hs[lane] = 0.0f;
    float h = 0.0f;
    const float* gxb = gx + (size_t)(b*TT + t0)*192;
    float c_r = gxb[lane], c_z = gxb[64+lane], c_n = gxb[128+lane];
    float n_r = 0.f, n_z = 0.f, n_n = 0.f;
    if (steps > 1) { n_r = gxb[192+lane]; n_z = gxb[256+lane]; n_n = gxb[320+lane]; }
    for (int s = 0; s < steps; s++) {
        float p_r = 0.f, p_z = 0.f, p_n = 0.f;
        if (s + 2 < steps) {
            const float* gp = gxb + (size_t)(s+2)*192;
            p_r = gp[lane]; p_z = gp[64+lane]; p_n = gp[128+lane];
        }
        const float* hh = hs + (s & 1)*HIDC;
        float ar = 0.f, az = 0.f, an = 0.f;
        #pragma unroll
        for (int k = 0; k < HIDC; k += 4) {
            float4 h4 = *(const float4*)&hh[k];
            ar = fmaf(h4.x, wr_[k],   ar); az = fmaf(h4.x, wz_[k],   az); an = fmaf(h4.x, wn_[k],   an);
            ar = fmaf(h4.y, wr_[k+1], ar); az = fmaf(h4.y, wz_[k+1], az); an = fmaf(h4.y, wn_[k+1], an);
            ar = fmaf(h4.z, wr_[k+2], ar); az = fmaf(h4.z, wz_[k+2], az); an = fmaf(h4.z, wn_[k+2], an);
            ar = fmaf(h4.w, wr_[k+3], ar); az = fmaf(h4.w, wz_[k+3], az); an = fmaf(h4.w, wn_[k+3], an);
        }
        float r = fsig(c_r + ar);          // b_ih + b_hh(r,z) folded into gx
        float z = fsig(c_z + az);
        float tg = ftanh(c_n + r*(bhn + an));
        h = (1.0f - z)*tg + z*h;
        hs[((s+1) & 1)*HIDC + lane] = h;
        hb[(size_t)s*HIDC + lane] = h;     // history for attention epilogue
        c_r = n_r; c_z = n_z; c_n = n_n;
        n_r = p_r; n_z = p_z; n_n = p_n;
    }
    float bap = b_ap[0];
    float* attn = out + (former ? (OUT_ATTF + b*SEQL) : (OUT_ATTA + b*PREDL));
    for (int t = lane; t < steps; t += 64) {
        const float* hr = hb + (size_t)t*HIDC;
        float a = 0.f;
        #pragma unroll 16
        for (int k = 0; k < HIDC; k++) a = fmaf(hr[k], w_ap[k], a);
        attn[t] = fsig(a + bap);
    }
}

extern "C" void kernel_launch(void* const* d_in, const int* in_sizes, int n_in,
                              void* d_out, int out_size, void* d_ws, size_t ws_size,
                              hipStream_t stream) {
    (void)in_sizes; (void)n_in; (void)out_size; (void)ws_size;
    const float* x       = (const float*)d_in[0];
    const float* dy      = (const float*)d_in[1];
    const int*   gi      = (const int*)  d_in[2];
    const float* dy_w    = (const float*)d_in[3];
    const float* dy_b    = (const float*)d_in[4];
    const float* w_seas  = (const float*)d_in[5];
    const float* b_seas  = (const float*)d_in[6];
    const float* w_trend = (const float*)d_in[7];
    const float* b_trend = (const float*)d_in[8];
    const float* w_res   = (const float*)d_in[9];
    const float* b_res   = (const float*)d_in[10];
    const float* w1_end  = (const float*)d_in[11];
    const float* b1_end  = (const float*)d_in[12];
    const float* w2_end  = (const float*)d_in[13];
    const float* b2_end  = (const float*)d_in[14];
    const float* w_ih    = (const float*)d_in[15];
    const float* w_hh    = (const float*)d_in[16];
    const float* b_ih    = (const float*)d_in[17];
    const float* b_hh    = (const float*)d_in[18];
    const float* w_ap    = (const float*)d_in[19];
    const float* b_ap    = (const float*)d_in[20];
    float* ws  = (float*)d_ws;
    float* out = (float*)d_out;

    hipLaunchKernelGGL(k_gm_gout, dim3(GG, BB), dim3(384), 0, stream,
                       x, gi, w_res, b_res, ws + OFF_GIN, ws + OFF_GOUT);
    hipLaunchKernelGGL(k_decomp, dim3((BB*NN*SEQL + 255)/256), dim3(256), 0, stream,
                       x, ws + OFF_SEAS, ws + OFF_TREND);
    hipLaunchKernelGGL(k_heads, dim3(BB*NN), dim3(128), 0, stream,
                       ws + OFF_SEAS, ws + OFF_TREND, gi, w_seas, b_seas, w_trend, b_trend,
                       ws + OFF_SEASO, ws + OFF_TRENDO);
    hipLaunchKernelGGL(k_mlp_all, dim3(7, 32), dim3(512), 0, stream,
                       ws + OFF_SEAS, ws + OFF_TREND, ws + OFF_SEASO, ws + OFF_TRENDO,
                       ws + OFF_GIN, ws + OFF_GOUT, gi, dy, dy_w, dy_b,
                       w1_end, b1_end, w2_end, b2_end,
                       w_ih, b_ih, b_hh, ws + OFF_GX, out);
    hipLaunchKernelGGL(k_gru, dim3(64), dim3(64), 0, stream,
                       ws + OFF_GX, w_hh, b_hh, w_ap, b_ap, ws + OFF_HIST, out);
}

// Round 6
// 799.339 us; speedup vs baseline: 1.0729x; 1.0729x over previous
//
#include <hip/hip_runtime.h>
#include <math.h>

#define BB 32
#define NN 128
#define SEQL 336
#define PREDL 96
#define DINC 16
#define DEMBC 32
#define HIDC 64
#define GG 8
#define KWIN 25
#define ENDC 34
#define TT 432

// workspace offsets (floats)
#define OFF_SEAS   0
#define OFF_TREND  (OFF_SEAS + BB*NN*SEQL)
#define OFF_GIN    (OFF_TREND + BB*NN*SEQL)
#define OFF_GOUT   (OFF_GIN + GG*BB*SEQL)
#define OFF_SEASO  (OFF_GOUT + GG*BB*PREDL)
#define OFF_TRENDO (OFF_SEASO + BB*NN*PREDL)
#define OFF_GX     (OFF_TRENDO + BB*NN*PREDL)
#define OFF_HIST   (OFF_GX + BB*TT*192)
// hist: former [32][336][64] then after [32][96][64]

// output offsets (floats)
#define OUT_FORMER 0
#define OUT_ATTF   (BB*NN*SEQL)
#define OUT_AFTER  (OUT_ATTF + BB*SEQL)
#define OUT_ATTA   (OUT_AFTER + BB*NN*PREDL)

__device__ __forceinline__ float fsig(float x) { return 1.0f/(1.0f + __expf(-x)); }
__device__ __forceinline__ float ftanh(float x) { return 1.0f - 2.0f/(__expf(2.0f*x) + 1.0f); }

// K1: per-group mean over member nodes + grouped residual head (fused)
__global__ __launch_bounds__(384) void k_gm_gout(const float* __restrict__ x,
                                                 const int* __restrict__ gi,
                                                 const float* __restrict__ w_res,
                                                 const float* __restrict__ b_res,
                                                 float* __restrict__ g_in,
                                                 float* __restrict__ g_out) {
    int g = blockIdx.x, b = blockIdx.y;
    __shared__ int sgi[NN];
    __shared__ float sg[SEQL];
    __shared__ float scnt;
    int tid = threadIdx.x;
    if (tid < NN) sgi[tid] = gi[tid];
    __syncthreads();
    if (tid == 0) {
        int c = 0;
        for (int n = 0; n < NN; n++) if (sgi[n] == g) c++;
        scnt = (float)c;
    }
    __syncthreads();
    float inv = 1.0f / scnt;
    for (int s = tid; s < SEQL; s += 384) {
        float sum = 0.0f;
        for (int n = 0; n < NN; n++)
            if (sgi[n] == g) sum += x[(b*NN + n)*SEQL + s];
        float v = sum * inv;
        sg[s] = v;
        g_in[(g*BB + b)*SEQL + s] = v;
    }
    __syncthreads();
    int p = tid;
    if (p < PREDL) {
        const float4* wr = (const float4*)(w_res + (g*PREDL + p)*SEQL);
        float acc = b_res[g*PREDL + p];
        #pragma unroll 4
        for (int s4 = 0; s4 < SEQL/4; s4++) {
            float4 w = wr[s4];
            float4 d = ((const float4*)sg)[s4];
            acc += w.x*d.x + w.y*d.y + w.z*d.z + w.w*d.w;
        }
        g_out[(g*BB + b)*PREDL + p] = acc;
    }
}

// K2: series decomposition: edge-padded moving average window 25
__global__ void k_decomp(const float* __restrict__ x, float* __restrict__ seasonal,
                         float* __restrict__ trend) {
    int idx = blockIdx.x*blockDim.x + threadIdx.x;
    if (idx >= BB*NN*SEQL) return;
    int t = idx % SEQL;
    int bn = idx / SEQL;
    const float* xr = x + bn*SEQL;
    float s = 0.0f;
    #pragma unroll
    for (int d = -12; d <= 12; d++) {
        int j = t + d;
        j = j < 0 ? 0 : (j >= SEQL ? SEQL-1 : j);
        s += xr[j];
    }
    float tr = s * (1.0f/KWIN);
    trend[idx] = tr;
    seasonal[idx] = xr[t] - tr;
}

// K3: per-node grouped seasonal/trend heads (SEQ->PRED), float4 everywhere
__global__ __launch_bounds__(128) void k_heads(const float* __restrict__ seasonal,
                                               const float* __restrict__ trend,
                                               const int* __restrict__ gi,
                                               const float* __restrict__ w_seas,
                                               const float* __restrict__ b_seas,
                                               const float* __restrict__ w_trend,
                                               const float* __restrict__ b_trend,
                                               float* __restrict__ seas_out,
                                               float* __restrict__ trend_out) {
    int bn = blockIdx.x;
    int n = bn % NN;
    int g = gi[n];
    __shared__ float ss[SEQL];
    __shared__ float st[SEQL];
    for (int s = threadIdx.x; s < SEQL/4; s += 128) {
        ((float4*)ss)[s] = ((const float4*)(seasonal + bn*SEQL))[s];
        ((float4*)st)[s] = ((const float4*)(trend + bn*SEQL))[s];
    }
    __syncthreads();
    int p = threadIdx.x;
    if (p < PREDL) {
        const float4* wsr = (const float4*)(w_seas + (g*PREDL + p)*SEQL);
        const float4* wtr = (const float4*)(w_trend + (g*PREDL + p)*SEQL);
        float a = b_seas[g*PREDL + p];
        float c = b_trend[g*PREDL + p];
        #pragma unroll 4
        for (int s4 = 0; s4 < SEQL/4; s4++) {
            float4 w0 = wsr[s4], w1 = wtr[s4];
            float4 d0 = ((const float4*)ss)[s4], d1 = ((const float4*)st)[s4];
            a += w0.x*d0.x + w0.y*d0.y + w0.z*d0.z + w0.w*d0.w;
            c += w1.x*d1.x + w1.y*d1.y + w1.z*d1.z + w1.w*d1.w;
        }
        seas_out[bn*PREDL + p] = a;
        trend_out[bn*PREDL + p] = c;
    }
}

// K4: mega-kernel: dy-emb + end-MLP outputs + node-mean + input-gate GEMM gx.
// Grid (7 t-tiles, 32 b), 512 thr = 64 t-lanes x 8 n-waves; wave w owns n = {w, w+8, ...}.
// RULE #20: every loop touching hv[]/dv[]/hsum[] is FULLY unrolled so all array
// indices are compile-time constants (round-4: "#pragma unroll 4" left `e` runtime
// -> hv in scratch -> VGPR=48, 170 MB spill writes).
__global__ __launch_bounds__(512, 1) void k_mlp_all(
    const float* __restrict__ seasonal, const float* __restrict__ trend,
    const float* __restrict__ seas_out, const float* __restrict__ trend_out,
    const float* __restrict__ g_in, const float* __restrict__ g_out,
    const int* __restrict__ gi, const float* __restrict__ dy,
    const float* __restrict__ dy_w, const float* __restrict__ dy_b,
    const float* __restrict__ w1_end, const float* __restrict__ b1_end,
    const float* __restrict__ w2_end, const float* __restrict__ b2_end,
    const float* __restrict__ w_ih, const float* __restrict__ b_ih,
    const float* __restrict__ b_hh, float* __restrict__ gx,
    float* __restrict__ out)
{
    __shared__ float s_wih[192][35];   // +1 pad: stride 35 -> <=2-way bank alias (free)
    __shared__ float s_hsum[64][35];
    int tile = blockIdx.x;             // 0..6
    int b = blockIdx.y;                // 0..31
    int tid = threadIdx.x;
    int lane = tid & 63, wave = tid >> 6;
    int t = tile*64 + lane;
    bool tvalid = (t < TT);
    int tc = tvalid ? t : (TT-1);

    for (int i = tid; i < 192*ENDC; i += 512) s_wih[i/ENDC][i%ENDC] = w_ih[i];
    for (int i = tid; i < 64*35; i += 512) (&s_hsum[0][0])[i] = 0.0f;
    __syncthreads();

    float hsum[ENDC];
    #pragma unroll
    for (int e = 0; e < ENDC; e++) hsum[e] = 0.0f;

    int wbase = __builtin_amdgcn_readfirstlane(wave);   // per-wave scalar

    for (int ni = 0; ni < 16; ni++) {
        int n = wbase + ni*8;                 // scalar -> gi[n] is s_load
        int bn = b*NN + n;
        int g = gi[n];
        const float4* dyr = (const float4*)(dy + ((size_t)bn*TT + tc)*DINC);
        float4 d0 = dyr[0], d1 = dyr[1], d2 = dyr[2], d3 = dyr[3];
        float dv[DINC] = {d0.x,d0.y,d0.z,d0.w, d1.x,d1.y,d1.z,d1.w,
                          d2.x,d2.y,d2.z,d2.w, d3.x,d3.y,d3.z,d3.w};
        float hv[ENDC];
        #pragma unroll                        // FULL unroll: static hv indices
        for (int e = 0; e < DEMBC; e++) {
            float a = dy_b[e];                // uniform -> sgpr
            #pragma unroll
            for (int i = 0; i < DINC; i++) a = fmaf(dv[i], dy_w[e*DINC + i], a);
            hv[2+e] = fmaxf(a, 0.0f);
        }
        float addv;
        if (tc < SEQL) {
            hv[0] = seasonal[bn*SEQL + tc];
            hv[1] = trend[bn*SEQL + tc];
            addv = g_in[(g*BB + b)*SEQL + tc];
        } else {
            int p = tc - SEQL;
            hv[0] = seas_out[bn*PREDL + p];
            hv[1] = trend_out[bn*PREDL + p];
            addv = g_out[(g*BB + b)*PREDL + p];
        }
        float acc = b2_end[g];
        const float* w1g = w1_end + g*HIDC*ENDC;
        const float* b1g = b1_end + g*HIDC;
        const float* w2g = w2_end + g*HIDC;
        #pragma unroll 4
        for (int hq = 0; hq < HIDC; hq++) {
            const float* wrow = w1g + hq*ENDC;   // uniform row -> s_load
            float a = b1g[hq];
            #pragma unroll                        // full: static hv reads
            for (int e = 0; e < ENDC; e++) a = fmaf(hv[e], wrow[e], a);
            acc = fmaf(fmaxf(a, 0.0f), w2g[hq], acc);
        }
        acc += addv;
        if (tvalid) {
            if (t < SEQL) out[OUT_FORMER + bn*SEQL + t] = acc;
            else          out[OUT_AFTER + bn*PREDL + (t - SEQL)] = acc;
        }
        #pragma unroll
        for (int e = 0; e < ENDC; e++) hsum[e] += hv[e];
    }

    // cross-wave reduction of hsum into s_hsum[lane][.]
    for (int w = 0; w < 8; w++) {
        if (wave == w) {
            #pragma unroll
            for (int e = 0; e < ENDC; e++) s_hsum[lane][e] += hsum[e];
        }
        __syncthreads();
    }
    for (int i = tid; i < 64*ENDC; i += 512) {
        int tt2 = i / ENDC, e = i % ENDC;
        s_hsum[tt2][e] *= (1.0f/NN);
    }
    __syncthreads();

    // gx for this (b, tile): 64 t x 192 j; consecutive tid -> consecutive j (coalesced)
    for (int it = 0; it < 24; it++) {
        int idx = tid + it*512;
        int j = idx % 192, tt2 = idx / 192;
        int tg = tile*64 + tt2;
        if (tg < TT) {
            float a = b_ih[j] + (j < 2*HIDC ? b_hh[j] : 0.0f);  // fold r,z hidden bias
            #pragma unroll
            for (int e = 0; e < ENDC; e++) a = fmaf(s_hsum[tt2][e], s_wih[j][e], a);
            gx[((size_t)b*TT + tg)*192 + j] = a;
        }
    }
}

// K5: dual GRU, standalone: 64 blocks x 64 threads.
// __launch_bounds__(64, 1): min 1 wave/EU -> VGPR cap 512, weights stay RESIDENT.
__global__ __launch_bounds__(64, 1) void k_gru(
    const float* __restrict__ gx, const float* __restrict__ w_hh,
    const float* __restrict__ b_hh, const float* __restrict__ w_ap,
    const float* __restrict__ b_ap, float* __restrict__ hist,
    float* __restrict__ out)
{
    __shared__ float hs[2*HIDC];
    int lane = threadIdx.x;
    int blk = blockIdx.x;
    int b = blk & 31;
    bool former = (blk < 32);
    int steps = former ? SEQL : PREDL;
    int t0 = former ? 0 : SEQL;
    float* hb = hist + (former ? (size_t)b*SEQL*HIDC
                               : (size_t)BB*SEQL*HIDC + (size_t)b*PREDL*HIDC);
    float wr_[HIDC], wz_[HIDC], wn_[HIDC];
    #pragma unroll
    for (int k = 0; k < HIDC; k++) wr_[k] = w_hh[lane*HIDC + k];
    #pragma unroll
    for (int k = 0; k < HIDC; k++) wz_[k] = w_hh[(lane+64)*HIDC + k];
    #pragma unroll
    for (int k = 0; k < HIDC; k++) wn_[k] = w_hh[(lane+128)*HIDC + k];
    float bhn = b_hh[lane + 128];
    hs[lane] = 0.0f;
    float h = 0.0f;
    const float* gxb = gx + (size_t)(b*TT + t0)*192;
    float c_r = gxb[lane], c_z = gxb[64+lane], c_n = gxb[128+lane];
    float n_r = 0.f, n_z = 0.f, n_n = 0.f;
    if (steps > 1) { n_r = gxb[192+lane]; n_z = gxb[256+lane]; n_n = gxb[320+lane]; }
    for (int s = 0; s < steps; s++) {
        float p_r = 0.f, p_z = 0.f, p_n = 0.f;
        if (s + 2 < steps) {
            const float* gp = gxb + (size_t)(s+2)*192;
            p_r = gp[lane]; p_z = gp[64+lane]; p_n = gp[128+lane];
        }
        const float* hh = hs + (s & 1)*HIDC;
        float ar = 0.f, az = 0.f, an = 0.f;
        #pragma unroll
        for (int k = 0; k < HIDC; k += 4) {
            float4 h4 = *(const float4*)&hh[k];
            ar = fmaf(h4.x, wr_[k],   ar); az = fmaf(h4.x, wz_[k],   az); an = fmaf(h4.x, wn_[k],   an);
            ar = fmaf(h4.y, wr_[k+1], ar); az = fmaf(h4.y, wz_[k+1], az); an = fmaf(h4.y, wn_[k+1], an);
            ar = fmaf(h4.z, wr_[k+2], ar); az = fmaf(h4.z, wz_[k+2], az); an = fmaf(h4.z, wn_[k+2], an);
            ar = fmaf(h4.w, wr_[k+3], ar); az = fmaf(h4.w, wz_[k+3], az); an = fmaf(h4.w, wn_[k+3], an);
        }
        float r = fsig(c_r + ar);          // b_ih + b_hh(r,z) folded into gx
        float z = fsig(c_z + az);
        float tg = ftanh(c_n + r*(bhn + an));
        h = (1.0f - z)*tg + z*h;
        hs[((s+1) & 1)*HIDC + lane] = h;
        hb[(size_t)s*HIDC + lane] = h;     // history for attention epilogue
        c_r = n_r; c_z = n_z; c_n = n_n;
        n_r = p_r; n_z = p_z; n_n = p_n;
    }
    float bap = b_ap[0];
    float* attn = out + (former ? (OUT_ATTF + b*SEQL) : (OUT_ATTA + b*PREDL));
    for (int t = lane; t < steps; t += 64) {
        const float* hr = hb + (size_t)t*HIDC;
        float a = 0.f;
        #pragma unroll 16
        for (int k = 0; k < HIDC; k++) a = fmaf(hr[k], w_ap[k], a);
        attn[t] = fsig(a + bap);
    }
}

extern "C" void kernel_launch(void* const* d_in, const int* in_sizes, int n_in,
                              void* d_out, int out_size, void* d_ws, size_t ws_size,
                              hipStream_t stream) {
    (void)in_sizes; (void)n_in; (void)out_size; (void)ws_size;
    const float* x       = (const float*)d_in[0];
    const float* dy      = (const float*)d_in[1];
    const int*   gi      = (const int*)  d_in[2];
    const float* dy_w    = (const float*)d_in[3];
    const float* dy_b    = (const float*)d_in[4];
    const float* w_seas  = (const float*)d_in[5];
    const float* b_seas  = (const float*)d_in[6];
    const float* w_trend = (const float*)d_in[7];
    const float* b_trend = (const float*)d_in[8];
    const float* w_res   = (const float*)d_in[9];
    const float* b_res   = (const float*)d_in[10];
    const float* w1_end  = (const float*)d_in[11];
    const float* b1_end  = (const float*)d_in[12];
    const float* w2_end  = (const float*)d_in[13];
    const float* b2_end  = (const float*)d_in[14];
    const float* w_ih    = (const float*)d_in[15];
    const float* w_hh    = (const float*)d_in[16];
    const float* b_ih    = (const float*)d_in[17];
    const float* b_hh    = (const float*)d_in[18];
    const float* w_ap    = (const float*)d_in[19];
    const float* b_ap    = (const float*)d_in[20];
    float* ws  = (float*)d_ws;
    float* out = (float*)d_out;

    hipLaunchKernelGGL(k_gm_gout, dim3(GG, BB), dim3(384), 0, stream,
                       x, gi, w_res, b_res, ws + OFF_GIN, ws + OFF_GOUT);
    hipLaunchKernelGGL(k_decomp, dim3((BB*NN*SEQL + 255)/256), dim3(256), 0, stream,
                       x, ws + OFF_SEAS, ws + OFF_TREND);
    hipLaunchKernelGGL(k_heads, dim3(BB*NN), dim3(128), 0, stream,
                       ws + OFF_SEAS, ws + OFF_TREND, gi, w_seas, b_seas, w_trend, b_trend,
                       ws + OFF_SEASO, ws + OFF_TRENDO);
    hipLaunchKernelGGL(k_mlp_all, dim3(7, 32), dim3(512), 0, stream,
                       ws + OFF_SEAS, ws + OFF_TREND, ws + OFF_SEASO, ws + OFF_TRENDO,
                       ws + OFF_GIN, ws + OFF_GOUT, gi, dy, dy_w, dy_b,
                       w1_end, b1_end, w2_end, b2_end,
                       w_ih, b_ih, b_hh, ws + OFF_GX, out);
    hipLaunchKernelGGL(k_gru, dim3(64), dim3(64), 0, stream,
                       ws + OFF_GX, w_hh, b_hh, w_ap, b_ap, ws + OFF_HIST, out);
}